// Round 2
// baseline (299.491 us; speedup 1.0000x reference)
//
#include <hip/hip_runtime.h>

#define E_EDGES 32768
#define NN 8192
#define HID 128
#define KS 4

typedef _Float16 half8 __attribute__((ext_vector_type(8)));
typedef _Float16 half4 __attribute__((ext_vector_type(4)));
typedef float f32x4 __attribute__((ext_vector_type(4)));

// ---------------- zero workspace accumulators (pools + per-layer agg) -----
__global__ void zero_all_k(float4* __restrict__ p, int n4) {
  int i = blockIdx.x * 256 + threadIdx.x;
  if (i < n4) p[i] = float4{0.f, 0.f, 0.f, 0.f};
}

// ---------------- W2 -> f16 B-matrix in MFMA-fragment-linear layout -------
// Linear padded k-space: k<128*CI theta rows (k=h*CI+i), next CI rows = b2
// (he==1 path), zero to Kpad. Layout: out[((k>>3)*CO + n)*8 + (k&7)] so a
// b-fragment (8 k x 16 n for one lane) is one contiguous 16B chunk.
template <int CI, int CO>
__device__ inline void prep_b_one(int idx, const float* __restrict__ W2,
                                  const float* __restrict__ b2, _Float16* __restrict__ out) {
  constexpr int Kmain = 128 * CI;
  int j = idx & 7;
  int n = (idx >> 3) & (CO - 1);
  int kg = idx >> (3 + (CO == 64 ? 6 : 5));
  int k = kg * 8 + j;
  float v = 0.f;
  if (k < Kmain) {
    int h = k / CI, i = k & (CI - 1);
    v = W2[(h * CI + i) * CO + n];
  } else if (k < Kmain + CI) {
    int tt = k - Kmain;
    v = b2[tt * CO + n];
  }
  out[idx] = (_Float16)v;
}

__global__ void prep_b_all_k(const float* __restrict__ W2_0, const float* __restrict__ b2_0, _Float16* __restrict__ o0,
                             const float* __restrict__ W2_1, const float* __restrict__ b2_1, _Float16* __restrict__ o1,
                             const float* __restrict__ W2_2, const float* __restrict__ b2_2, _Float16* __restrict__ o2) {
  constexpr int N0 = 2176 * 32;
  constexpr int N1 = 4224 * 64;
  constexpr int N2 = 8320 * 64;
  int idx = blockIdx.x * 256 + threadIdx.x;
  if (idx < N0) prep_b_one<16, 32>(idx, W2_0, b2_0, o0);
  else if (idx < N0 + N1) prep_b_one<32, 64>(idx - N0, W2_1, b2_1, o1);
  else if (idx < N0 + N1 + N2) prep_b_one<64, 64>(idx - N0 - N1, W2_2, b2_2, o2);
}

// ---------------- main fused kernel: edge MLP1 + Z@W2r GEMM (split-K=4) ---
// Barrier-free K-loop. A[e, h*CI+i] = he[e,h] * x[e,i] is a Khatri-Rao
// product: x fragments hoisted to registers once; he read packed per round.
// Epilogue: fused scatter-add -> agg[dst][o] via atomicAdd (msgbuf and the
// whole CSR build are gone; agg is 1-2 MB, L2-resident, avg 16 hits/line).
template <int CI, int CO>
__launch_bounds__(256, 2)
__global__ void msg_mfma_k(const float* __restrict__ xcur, const int* __restrict__ src,
                           const int* __restrict__ dst,
                           const float* __restrict__ eattr, const float* __restrict__ W1,
                           const float* __restrict__ b1, const _Float16* __restrict__ Bsw,
                           float* __restrict__ agg) {
  constexpr int ME = 256;                      // edges per block
  constexpr int L2CI = (CI == 64) ? 6 : ((CI == 32) ? 5 : 4);
  constexpr int XSTR = CI + 8;                 // x tile pad (preload-only)
  constexpr int HSTR = 40;                     // he [e][40] f16: 8B-aligned rows
  constexpr int FC = CO / 16;
  constexpr int C4 = CI / 4;
  constexpr int L2C4 = L2CI - 2;
  constexpr int NMAIN = CI / 4;                // main rounds per split (all y)
  constexpr int XPN = (CI == 64) ? 2 : 1;      // x fragments per (fr): c-parity

  __shared__ _Float16 he_s[ME * HSTR];         // [e][h-local] transposed
  __shared__ _Float16 xs_s[ME * XSTR];         // [e][i]
  __shared__ float ea_s[ME * 5];
  __shared__ float W1s[5 * 32];
  __shared__ float b1s[32];
  __shared__ int src_s[ME];
  __shared__ int dst_s[ME];

  int t = threadIdx.x;
  int e0 = blockIdx.x * ME;
  int y = blockIdx.y;                          // split: h in [32y, 32y+32)
  int hbeg = y * 32;

  // phase 1: stage eattr rows, W1/b1 slice, src/dst indices
  for (int j = t; j < ME * 5; j += 256) ea_s[j] = eattr[e0 * 5 + j];
  if (t < 5 * 32) W1s[t] = W1[(t >> 5) * HID + hbeg + (t & 31)];
  if (t < 32) b1s[t] = b1[hbeg + t];
  src_s[t] = src[e0 + t];
  dst_s[t] = dst[e0 + t];
  __syncthreads();

  // phase 2: edge MLP1 — hl fastest across lanes: he store is 2B-contiguous
  // (2-way alias, free) instead of stride-80B (16-way conflict).
  for (int j = t; j < 32 * ME; j += 256) {
    int hl = j & 31, e = j >> 5;
    float v = b1s[hl];
#pragma unroll
    for (int d = 0; d < 5; ++d) v += ea_s[e * 5 + d] * W1s[d * 32 + hl];
    he_s[e * HSTR + hl] = (_Float16)fmaxf(v, 0.f);
  }
  for (int j = t; j < ME * C4; j += 256) {
    int e = j >> L2C4, i4 = j & (C4 - 1);
    float4 v = ((const float4*)xcur)[src_s[e] * C4 + i4];
    half4 hq = {(_Float16)v.x, (_Float16)v.y, (_Float16)v.z, (_Float16)v.w};
    *(half4*)&xs_s[e * XSTR + i4 * 4] = hq;
  }
  __syncthreads();                             // last barrier before K-loop

  int lane = t & 63;
  int w = t >> 6;
  int quad = lane >> 4, l15 = lane & 15;
  int qsh = (quad >> 1) << 4;                  // CI==16 h-pair select shift

  int cbeg = y * CI;                           // SPLITK/32 == CI
  int cend = cbeg + CI + ((y == 3) ? 4 : 0);   // TAILK/32 == CI+4

  const half8* bsw8 = (const half8*)Bsw;
  int ib = quad * CO + l15;                    // per-lane b-frag offset

  // one-time register preload: x fragments + he row base pointers
  half8 xp[4][XPN];
  const _Float16* hbp[4];
#pragma unroll
  for (int fr = 0; fr < 4; ++fr) {
    int e = w * 64 + fr * 16 + l15;
    int i0 = (CI == 16) ? ((quad & 1) * 8) : (quad * 8);
    xp[fr][0] = *(const half8*)&xs_s[e * XSTR + i0];
    if constexpr (CI == 64) xp[fr][1] = *(const half8*)&xs_s[e * XSTR + i0 + 32];
    hbp[fr] = he_s + e * HSTR;
  }

  f32x4 acc[4][FC];
#pragma unroll
  for (int fr = 0; fr < 4; ++fr)
#pragma unroll
    for (int fc = 0; fc < FC; ++fc)
#pragma unroll
      for (int r = 0; r < 4; ++r) acc[fr][fc][r] = 0.f;

  // preload B fragments for first 4 chunks
  half8 breg[4][FC];
#pragma unroll
  for (int j = 0; j < 4; ++j)
#pragma unroll
    for (int fc = 0; fc < FC; ++fc)
      breg[j][fc] = bsw8[(cbeg + j) * 4 * CO + ib + fc * 16];

  for (int r = 0; r < NMAIN; ++r) {
    int c0 = cbeg + r * 4;
    // packed he loads for the whole round
    unsigned int hp2[4];                       // CI==64: {h0, h0+1}
    half4 hp4[4];                              // CI==32: {h0..h0+3}
    if constexpr (CI == 64) {
      int oh = (c0 >> 1) - hbeg;
#pragma unroll
      for (int fr = 0; fr < 4; ++fr) hp2[fr] = *(const unsigned int*)(hbp[fr] + oh);
    } else if constexpr (CI == 32) {
      int oh = c0 - hbeg;
#pragma unroll
      for (int fr = 0; fr < 4; ++fr) hp4[fr] = *(const half4*)(hbp[fr] + oh);
    }
#pragma unroll
    for (int j = 0; j < 4; ++j) {
      int c = c0 + j;
      half8 a[4];
#pragma unroll
      for (int fr = 0; fr < 4; ++fr) {
        if constexpr (CI == 64) {
          unsigned short hb = (unsigned short)((j >= 2) ? (hp2[fr] >> 16) : hp2[fr]);
          _Float16 hv = __builtin_bit_cast(_Float16, hb);
          a[fr] = xp[fr][j & 1] * hv;
        } else if constexpr (CI == 32) {
          a[fr] = xp[fr][0] * hp4[fr][j];
        } else {
          unsigned int hw = *(const unsigned int*)(hbp[fr] + (2 * c - hbeg));
          _Float16 hv = __builtin_bit_cast(_Float16, (unsigned short)(hw >> qsh));
          a[fr] = xp[fr][0] * hv;
        }
      }
#pragma unroll
      for (int fc = 0; fc < FC; ++fc) {
#pragma unroll
        for (int fr = 0; fr < 4; ++fr)
          acc[fr][fc] = __builtin_amdgcn_mfma_f32_16x16x32_f16(a[fr], breg[j][fc], acc[fr][fc], 0, 0, 0);
      }
      int cn = c + 4;
      if (cn >= cend) cn = cend - 1;           // clamped: branch-free prefetch
#pragma unroll
      for (int fc = 0; fc < FC; ++fc)
        breg[j][fc] = bsw8[cn * 4 * CO + ib + fc * 16];
    }
  }

  // y==3 only: single tail round (b2 rows: A = x, he == 1; zero-pad B)
  if (y == 3) {
#pragma unroll
    for (int j = 0; j < 4; ++j) {
      half8 a[4];
#pragma unroll
      for (int fr = 0; fr < 4; ++fr) a[fr] = xp[fr][(CI == 64) ? (j & 1) : 0];
#pragma unroll
      for (int fc = 0; fc < FC; ++fc) {
#pragma unroll
        for (int fr = 0; fr < 4; ++fr)
          acc[fr][fc] = __builtin_amdgcn_mfma_f32_16x16x32_f16(a[fr], breg[j][fc], acc[fr][fc], 0, 0, 0);
      }
    }
  }

  // epilogue: fused scatter-add into agg (C/D: row(e)=quad*4+r, col(o)=l15)
#pragma unroll
  for (int fr = 0; fr < 4; ++fr) {
    int dcache[4];
#pragma unroll
    for (int r = 0; r < 4; ++r) dcache[r] = dst_s[w * 64 + fr * 16 + quad * 4 + r];
#pragma unroll
    for (int fc = 0; fc < FC; ++fc)
#pragma unroll
      for (int r = 0; r < 4; ++r) {
        int o = fc * 16 + l15;
        atomicAdd(&agg[(size_t)dcache[r] * CO + o], acc[fr][fc][r]);
      }
  }
}

// ---------------- per-node: agg + x@root + bias + ELU ---------------------
// POOL=true (last layer): skip x-write, atomically accumulate subgraph pools.
template <int CI, int CO, bool POOL>
__global__ void node_elu_k(const float* __restrict__ xcur, const float* __restrict__ root,
                           const float* __restrict__ bias, const float* __restrict__ agg,
                           float* __restrict__ xnext, const int* __restrict__ n2s,
                           float* __restrict__ ssum, float* __restrict__ scnt) {
  constexpr int NB = 256 / CO;
  __shared__ float xs[NB * CI];
  int t = threadIdx.x;
  int n0 = blockIdx.x * NB;
  for (int j = t; j < NB * CI; j += 256) xs[j] = xcur[n0 * CI + j];
  __syncthreads();
  int nl = t / CO, o = t & (CO - 1);
  int n = n0 + nl;
  float a = bias[o] + agg[(size_t)n * CO + o];
#pragma unroll
  for (int i = 0; i < CI; ++i) a += xs[nl * CI + i] * root[i * CO + o];
  float v = a > 0.f ? a : expm1f(a);
  if constexpr (POOL) {
    int s = n2s[n];
    atomicAdd(&ssum[(s << 6) + o], v);
    if (o == 0) atomicAdd(&scnt[s], 1.f);
  } else {
    xnext[n * CO + o] = v;
  }
}

// ---------------- graph pooling + MLP head (fused) ------------------------
__global__ void pg_head_k(const float* __restrict__ ssum, const float* __restrict__ scnt,
                          const int* __restrict__ s2g,
                          const float* __restrict__ w1, const float* __restrict__ b1,
                          const float* __restrict__ w2, const float* __restrict__ b2,
                          const float* __restrict__ w3, const float* __restrict__ b3,
                          float* __restrict__ out) {
  int g = blockIdx.x;
  int t = threadIdx.x;  // 64 threads
  __shared__ int s2s[512];
  __shared__ float hm[64], h1[32], h2[16];
  for (int i = t; i < 512; i += 64) s2s[i] = s2g[i];
  __syncthreads();
  float acc = 0.f, cnt = 0.f;
  for (int s = 0; s < 512; ++s) {
    if (s2s[s] == g) {
      acc += ssum[(s << 6) + t] / fmaxf(scnt[s], 1.f);
      cnt += 1.f;
    }
  }
  hm[t] = acc / fmaxf(cnt, 1.f);
  __syncthreads();
  if (t < 32) {
    float a = b1[t];
    for (int i = 0; i < 64; ++i) a += hm[i] * w1[i * 32 + t];
    h1[t] = a > 0.f ? a : expm1f(a);
  }
  __syncthreads();
  if (t < 16) {
    float a = b2[t];
    for (int i = 0; i < 32; ++i) a += h1[i] * w2[i * 16 + t];
    h2[t] = a > 0.f ? a : expm1f(a);
  }
  __syncthreads();
  if (t == 0) {
    float a = b3[0];
    for (int i = 0; i < 16; ++i) a += h2[i] * w3[i];
    out[g] = a;
  }
}

extern "C" void kernel_launch(void* const* d_in, const int* in_sizes, int n_in,
                              void* d_out, int out_size, void* d_ws, size_t ws_size,
                              hipStream_t stream) {
  (void)in_sizes; (void)n_in; (void)out_size; (void)ws_size;
  const float* x0 = (const float*)d_in[0];
  const int* ei = (const int*)d_in[1];
  const float* ea = (const float*)d_in[2];
  const int* n2s = (const int*)d_in[3];
  const int* s2g = (const int*)d_in[4];
  const float* W1_[3] = {(const float*)d_in[5], (const float*)d_in[11], (const float*)d_in[17]};
  const float* b1_[3] = {(const float*)d_in[6], (const float*)d_in[12], (const float*)d_in[18]};
  const float* W2_[3] = {(const float*)d_in[7], (const float*)d_in[13], (const float*)d_in[19]};
  const float* b2_[3] = {(const float*)d_in[8], (const float*)d_in[14], (const float*)d_in[20]};
  const float* rt_[3] = {(const float*)d_in[9], (const float*)d_in[15], (const float*)d_in[21]};
  const float* bs_[3] = {(const float*)d_in[10], (const float*)d_in[16], (const float*)d_in[22]};
  const float* fc1w = (const float*)d_in[23]; const float* fc1b = (const float*)d_in[24];
  const float* fc2w = (const float*)d_in[25]; const float* fc2b = (const float*)d_in[26];
  const float* fc3w = (const float*)d_in[27]; const float* fc3b = (const float*)d_in[28];
  float* out = (float*)d_out;

  const int* srcp = ei;
  const int* dstp = ei + E_EDGES;

  char* wsb = (char*)d_ws;
  size_t off = 0;
  auto alloc = [&](size_t bytes) {
    void* p = wsb + off;
    off += (bytes + 255) & ~(size_t)255;
    return p;
  };
  // Kpad: L0(CI=16): 2176, L1(CI=32): 4224, L2(CI=64): 8320
  _Float16* Bsw0 = (_Float16*)alloc((size_t)2176 * 32 * 2);
  _Float16* Bsw1 = (_Float16*)alloc((size_t)4224 * 64 * 2);
  _Float16* Bsw2 = (_Float16*)alloc((size_t)8320 * 64 * 2);
  // contiguous zeroed region: pools | agg0 | agg1 | agg2
  const int npool = 512 * 64 + 512;            // 33280 floats (133120 B, 256B-mult)
  const int nagg0 = NN * 32, nagg1 = NN * 64, nagg2 = NN * 64;
  const int nzero = npool + nagg0 + nagg1 + nagg2;
  float* zbase = (float*)alloc((size_t)nzero * 4);
  float* ssum = zbase;
  float* scnt = zbase + 512 * 64;
  float* agg0 = zbase + npool;
  float* agg1 = agg0 + nagg0;
  float* agg2 = agg1 + nagg1;
  float* x1 = (float*)alloc((size_t)NN * 32 * 4);
  float* x2 = (float*)alloc((size_t)NN * 64 * 4);

  const int n4 = nzero / 4;
  zero_all_k<<<(n4 + 255) / 256, 256, 0, stream>>>((float4*)zbase, n4);
  prep_b_all_k<<<(2176 * 32 + 4224 * 64 + 8320 * 64) / 256, 256, 0, stream>>>(
      W2_[0], b2_[0], Bsw0, W2_[1], b2_[1], Bsw1, W2_[2], b2_[2], Bsw2);

  dim3 mg(E_EDGES / 256, KS);
  msg_mfma_k<16, 32><<<mg, 256, 0, stream>>>(x0, srcp, dstp, ea, W1_[0], b1_[0], Bsw0, agg0);
  node_elu_k<16, 32, false><<<NN / 8, 256, 0, stream>>>(x0, rt_[0], bs_[0], agg0, x1, nullptr, nullptr, nullptr);
  msg_mfma_k<32, 64><<<mg, 256, 0, stream>>>(x1, srcp, dstp, ea, W1_[1], b1_[1], Bsw1, agg1);
  node_elu_k<32, 64, false><<<NN / 4, 256, 0, stream>>>(x1, rt_[1], bs_[1], agg1, x2, nullptr, nullptr, nullptr);
  msg_mfma_k<64, 64><<<mg, 256, 0, stream>>>(x2, srcp, dstp, ea, W1_[2], b1_[2], Bsw2, agg2);
  node_elu_k<64, 64, true><<<NN / 4, 256, 0, stream>>>(x2, rt_[2], bs_[2], agg2, nullptr, n2s, ssum, scnt);

  pg_head_k<<<32, 64, 0, stream>>>(ssum, scnt, s2g, fc1w, fc1b, fc2w, fc2b, fc3w, fc3b, out);
}

// Round 3
// 298.319 us; speedup vs baseline: 1.0039x; 1.0039x over previous
//
#include <hip/hip_runtime.h>

#define E_EDGES 32768
#define NN 8192
#define HID 128
#define KS 4

typedef _Float16 half8 __attribute__((ext_vector_type(8)));
typedef _Float16 half4 __attribute__((ext_vector_type(4)));
typedef float f32x4 __attribute__((ext_vector_type(4)));

// ---------------- CSR build (by dst), done once per call ----------------
__global__ void zero_init_k(int* __restrict__ hist, float* __restrict__ pools, int npool) {
  int t = blockIdx.x * 256 + threadIdx.x;
  if (t < NN) hist[t] = 0;
  if (t < npool) pools[t] = 0.f;
}

__global__ void hist_k(const int* __restrict__ dst, int* __restrict__ hist) {
  int e = blockIdx.x * 256 + threadIdx.x;
  if (e < E_EDGES) atomicAdd(&hist[dst[e]], 1);
}

__global__ void scan_k(const int* __restrict__ hist, int* __restrict__ roff, int* __restrict__ cursor) {
  __shared__ int ps[1024];
  int t = threadIdx.x;
  int loc[8]; int s = 0;
  int base = t * 8;
#pragma unroll
  for (int j = 0; j < 8; ++j) { loc[j] = s; s += hist[base + j]; }
  ps[t] = s;
  __syncthreads();
  for (int off = 1; off < 1024; off <<= 1) {
    int v = 0;
    if (t >= off) v = ps[t - off];
    __syncthreads();
    if (t >= off) ps[t] += v;
    __syncthreads();
  }
  int excl = (t == 0) ? 0 : ps[t - 1];
#pragma unroll
  for (int j = 0; j < 8; ++j) { int v = excl + loc[j]; roff[base + j] = v; cursor[base + j] = v; }
  if (t == 1023) roff[NN] = ps[1023];
}

__global__ void scatter_k(const int* __restrict__ dst, int* __restrict__ cursor, int* __restrict__ eidx) {
  int e = blockIdx.x * 256 + threadIdx.x;
  if (e < E_EDGES) { int p = atomicAdd(&cursor[dst[e]], 1); eidx[p] = e; }
}

// ---------------- W2 -> f16 B-matrix in MFMA-fragment-linear layout -------
// Linear padded k-space: k<128*CI theta rows (k=h*CI+i), next CI rows = b2
// (he==1 path), zero to Kpad. Layout: out[((k>>3)*CO + n)*8 + (k&7)] so a
// b-fragment (8 k x 16 n for one lane) is one contiguous 16B chunk.
template <int CI, int CO>
__device__ inline void prep_b_one(int idx, const float* __restrict__ W2,
                                  const float* __restrict__ b2, _Float16* __restrict__ out) {
  constexpr int Kmain = 128 * CI;
  int j = idx & 7;
  int n = (idx >> 3) & (CO - 1);
  int kg = idx >> (3 + (CO == 64 ? 6 : 5));
  int k = kg * 8 + j;
  float v = 0.f;
  if (k < Kmain) {
    int h = k / CI, i = k & (CI - 1);
    v = W2[(h * CI + i) * CO + n];
  } else if (k < Kmain + CI) {
    int tt = k - Kmain;
    v = b2[tt * CO + n];
  }
  out[idx] = (_Float16)v;
}

__global__ void prep_b_all_k(const float* __restrict__ W2_0, const float* __restrict__ b2_0, _Float16* __restrict__ o0,
                             const float* __restrict__ W2_1, const float* __restrict__ b2_1, _Float16* __restrict__ o1,
                             const float* __restrict__ W2_2, const float* __restrict__ b2_2, _Float16* __restrict__ o2) {
  constexpr int N0 = 2176 * 32;
  constexpr int N1 = 4224 * 64;
  constexpr int N2 = 8320 * 64;
  int idx = blockIdx.x * 256 + threadIdx.x;
  if (idx < N0) prep_b_one<16, 32>(idx, W2_0, b2_0, o0);
  else if (idx < N0 + N1) prep_b_one<32, 64>(idx - N0, W2_1, b2_1, o1);
  else if (idx < N0 + N1 + N2) prep_b_one<64, 64>(idx - N0 - N1, W2_2, b2_2, o2);
}

__device__ inline half8 pack8(float4 a, float4 b) {
  half8 r;
  r[0] = (_Float16)a.x; r[1] = (_Float16)a.y; r[2] = (_Float16)a.z; r[3] = (_Float16)a.w;
  r[4] = (_Float16)b.x; r[5] = (_Float16)b.y; r[6] = (_Float16)b.z; r[7] = (_Float16)b.w;
  return r;
}

// ---------------- main fused kernel: edge MLP1 + Z@W2r GEMM (split-K=4) ---
// ME=128 edges/block -> grid 1024 = 4 blocks/CU (was 2: occupancy was
// grid-limited at 16%). x fragments gathered DIRECTLY global->reg (each row
// read once per block; x is L2-resident) so xs_s LDS is gone: ~13 KB LDS.
// launch_bounds(256,4) caps VGPR <=128 so 4 blocks/CU actually fit.
// A[e, h*CI+i] = he[e,h]*x[e,i] (Khatri-Rao): x frags K-invariant in reg,
// he read as packed b32/b64 per 4-chunk round. B streamed from global with
// depth-2 rotating register prefetch; no barrier in the K-loop.
// Epilogue: plain streaming msgbuf writes (atomics write through to HBM on
// this chip -- measured WRITE_SIZE == full atomic byte count in round 2).
template <int CI, int CO>
__launch_bounds__(256, 4)
__global__ void msg_mfma_k(const float* __restrict__ xcur, const int* __restrict__ src,
                           const float* __restrict__ eattr, const float* __restrict__ W1,
                           const float* __restrict__ b1, const _Float16* __restrict__ Bsw,
                           float* __restrict__ msgbuf) {
  constexpr int ME = 128;                      // edges per block
  constexpr int HSTR = 36;                     // he [e][36] f16: 72B rows, 1-2 way banks
  constexpr int FC = CO / 16;
  constexpr int NMAIN = CI / 4;                // main rounds per split (all y)
  constexpr int XPN = (CI == 64) ? 2 : 1;

  __shared__ _Float16 he_s[ME * HSTR];         // [e][h-local]
  __shared__ float ea_s[ME * 5];
  __shared__ float W1s[5 * 32];
  __shared__ float b1s[32];
  __shared__ int src_s[ME];

  int t = threadIdx.x;
  int e0 = blockIdx.x * ME;
  int y = blockIdx.y;                          // split: h in [32y, 32y+32)
  int hbeg = y * 32;

  // phase 1: stage eattr rows, W1/b1 slice, src indices
  for (int j = t; j < ME * 5; j += 256) ea_s[j] = eattr[e0 * 5 + j];
  if (t < 5 * 32) W1s[t] = W1[(t >> 5) * HID + hbeg + (t & 31)];
  if (t < 32) b1s[t] = b1[hbeg + t];
  if (t < ME) src_s[t] = src[e0 + t];
  __syncthreads();

  // phase 2: edge MLP1 (this split's 32 h). hl fastest across lanes:
  // stores are 2B-contiguous (free 2-way alias), W1s reads conflict-free.
  for (int j = t; j < 32 * ME; j += 256) {
    int hl = j & 31, e = j >> 5;
    float v = b1s[hl];
#pragma unroll
    for (int d = 0; d < 5; ++d) v += ea_s[e * 5 + d] * W1s[d * 32 + hl];
    he_s[e * HSTR + hl] = (_Float16)fmaxf(v, 0.f);
  }
  __syncthreads();                             // last barrier before K-loop

  int lane = t & 63;
  int w = t >> 6;
  int quad = lane >> 4, l15 = lane & 15;
  int qsh = (quad >> 1) << 4;                  // CI==16 h-pair select shift

  int cbeg = y * CI;                           // SPLITK/32 == CI
  int cend = cbeg + CI + ((y == 3) ? 4 : 0);   // +4 tail chunks on y==3

  const half8* bsw8 = (const half8*)Bsw;
  int ib = quad * CO + l15;                    // per-lane b-frag offset

  // one-time preload: x fragments direct from global, he row base pointers
  half8 xp[2][XPN];
  const _Float16* hbp[2];
#pragma unroll
  for (int fr = 0; fr < 2; ++fr) {
    int e = w * 32 + fr * 16 + l15;
    const float* xr = xcur + (size_t)src_s[e] * CI;
    int i0 = (CI == 16) ? ((quad & 1) * 8) : (quad * 8);
    float4 v0 = *(const float4*)(xr + i0);
    float4 v1 = *(const float4*)(xr + i0 + 4);
    xp[fr][0] = pack8(v0, v1);
    if constexpr (CI == 64) {
      float4 v2 = *(const float4*)(xr + i0 + 32);
      float4 v3 = *(const float4*)(xr + i0 + 36);
      xp[fr][1] = pack8(v2, v3);
    }
    hbp[fr] = he_s + e * HSTR;
  }

  f32x4 acc[2][FC];
#pragma unroll
  for (int fr = 0; fr < 2; ++fr)
#pragma unroll
    for (int fc = 0; fc < FC; ++fc)
#pragma unroll
      for (int r = 0; r < 4; ++r) acc[fr][fc][r] = 0.f;

  // depth-2 rotating B prefetch: slot = chunk parity
  half8 breg[2][FC];
#pragma unroll
  for (int sl = 0; sl < 2; ++sl)
#pragma unroll
    for (int fc = 0; fc < FC; ++fc)
      breg[sl][fc] = bsw8[(cbeg + sl) * 4 * CO + ib + fc * 16];

  for (int r = 0; r < NMAIN; ++r) {
    int c0 = cbeg + r * 4;
    // packed he loads for the whole round
    unsigned int hp2[2];                       // CI==64: {h0, h0+1}
    half4 hp4[2];                              // CI==32: {h0..h0+3}
    if constexpr (CI == 64) {
      int oh = (c0 >> 1) - hbeg;
#pragma unroll
      for (int fr = 0; fr < 2; ++fr) hp2[fr] = *(const unsigned int*)(hbp[fr] + oh);
    } else if constexpr (CI == 32) {
      int oh = c0 - hbeg;
#pragma unroll
      for (int fr = 0; fr < 2; ++fr) hp4[fr] = *(const half4*)(hbp[fr] + oh);
    }
#pragma unroll
    for (int j = 0; j < 4; ++j) {
      int c = c0 + j;
      int sl = j & 1;
      half8 a[2];
#pragma unroll
      for (int fr = 0; fr < 2; ++fr) {
        if constexpr (CI == 64) {
          unsigned short hb = (unsigned short)((j >= 2) ? (hp2[fr] >> 16) : hp2[fr]);
          _Float16 hv = __builtin_bit_cast(_Float16, hb);
          a[fr] = xp[fr][j & 1] * hv;
        } else if constexpr (CI == 32) {
          a[fr] = xp[fr][0] * hp4[fr][j];
        } else {
          unsigned int hw = *(const unsigned int*)(hbp[fr] + (2 * c - hbeg));
          _Float16 hv = __builtin_bit_cast(_Float16, (unsigned short)(hw >> qsh));
          a[fr] = xp[fr][0] * hv;
        }
      }
#pragma unroll
      for (int fc = 0; fc < FC; ++fc) {
#pragma unroll
        for (int fr = 0; fr < 2; ++fr)
          acc[fr][fc] = __builtin_amdgcn_mfma_f32_16x16x32_f16(a[fr], breg[sl][fc], acc[fr][fc], 0, 0, 0);
      }
      int cn = c + 2;
      if (cn >= cend) cn = cend - 1;           // clamped: branch-free prefetch
#pragma unroll
      for (int fc = 0; fc < FC; ++fc)
        breg[sl][fc] = bsw8[cn * 4 * CO + ib + fc * 16];
    }
  }

  // y==3 only: single tail round (b2 rows: A = x, he == 1; zero-pad B)
  if (y == 3) {
#pragma unroll
    for (int j = 0; j < 4; ++j) {
      int sl = j & 1;
      half8 a[2];
#pragma unroll
      for (int fr = 0; fr < 2; ++fr) a[fr] = xp[fr][(CI == 64) ? (j & 1) : 0];
#pragma unroll
      for (int fc = 0; fc < FC; ++fc) {
#pragma unroll
        for (int fr = 0; fr < 2; ++fr)
          acc[fr][fc] = __builtin_amdgcn_mfma_f32_16x16x32_f16(a[fr], breg[sl][fc], acc[fr][fc], 0, 0, 0);
      }
      int cn = cbeg + CI + j + 2;
      if (cn >= cend) cn = cend - 1;
#pragma unroll
      for (int fc = 0; fc < FC; ++fc)
        breg[sl][fc] = bsw8[cn * 4 * CO + ib + fc * 16];
    }
  }

  // epilogue: streaming partial writes; C/D: row(e)=quad*4+r, col(o)=l15
  float* mb = msgbuf + ((size_t)y * E_EDGES + e0) * CO;
#pragma unroll
  for (int fr = 0; fr < 2; ++fr)
#pragma unroll
    for (int fc = 0; fc < FC; ++fc)
#pragma unroll
      for (int r = 0; r < 4; ++r) {
        int el = w * 32 + fr * 16 + quad * 4 + r;
        int o = fc * 16 + l15;
        mb[el * CO + o] = acc[fr][fc][r];
      }
}

// ---------------- scatter-sum via CSR gather + x@root + bias + ELU --------
// POOL=true (last layer): skip x-write, atomically accumulate subgraph pools.
template <int CI, int CO, bool POOL>
__global__ void gather_elu_k(const float* __restrict__ xcur, const float* __restrict__ root,
                             const float* __restrict__ bias, const float* __restrict__ msgbuf,
                             const int* __restrict__ roff, const int* __restrict__ eidx,
                             float* __restrict__ xnext, const int* __restrict__ n2s,
                             float* __restrict__ ssum, float* __restrict__ scnt) {
  constexpr int NB = 256 / CO;
  __shared__ float xs[NB * CI];
  int t = threadIdx.x;
  int n0 = blockIdx.x * NB;
  for (int j = t; j < NB * CI; j += 256) xs[j] = xcur[n0 * CI + j];
  __syncthreads();
  int nl = t / CO, o = t & (CO - 1);
  int n = n0 + nl;
  float a = bias[o];
#pragma unroll
  for (int i = 0; i < CI; ++i) a += xs[nl * CI + i] * root[i * CO + o];
  int j1 = roff[n + 1];
  for (int j = roff[n]; j < j1; ++j) {
    int e = eidx[j];
    float m = 0.f;
#pragma unroll
    for (int s = 0; s < KS; ++s) m += msgbuf[((size_t)s * E_EDGES + e) * CO + o];
    a += m;
  }
  float v = a > 0.f ? a : expm1f(a);
  if constexpr (POOL) {
    int s = n2s[n];
    atomicAdd(&ssum[(s << 6) + o], v);
    if (o == 0) atomicAdd(&scnt[s], 1.f);
  } else {
    xnext[n * CO + o] = v;
  }
}

// ---------------- graph pooling + MLP head (fused) ------------------------
__global__ void pg_head_k(const float* __restrict__ ssum, const float* __restrict__ scnt,
                          const int* __restrict__ s2g,
                          const float* __restrict__ w1, const float* __restrict__ b1,
                          const float* __restrict__ w2, const float* __restrict__ b2,
                          const float* __restrict__ w3, const float* __restrict__ b3,
                          float* __restrict__ out) {
  int g = blockIdx.x;
  int t = threadIdx.x;  // 64 threads
  __shared__ int s2s[512];
  __shared__ float hm[64], h1[32], h2[16];
  for (int i = t; i < 512; i += 64) s2s[i] = s2g[i];
  __syncthreads();
  float acc = 0.f, cnt = 0.f;
  for (int s = 0; s < 512; ++s) {
    if (s2s[s] == g) {
      acc += ssum[(s << 6) + t] / fmaxf(scnt[s], 1.f);
      cnt += 1.f;
    }
  }
  hm[t] = acc / fmaxf(cnt, 1.f);
  __syncthreads();
  if (t < 32) {
    float a = b1[t];
    for (int i = 0; i < 64; ++i) a += hm[i] * w1[i * 32 + t];
    h1[t] = a > 0.f ? a : expm1f(a);
  }
  __syncthreads();
  if (t < 16) {
    float a = b2[t];
    for (int i = 0; i < 32; ++i) a += h1[i] * w2[i * 16 + t];
    h2[t] = a > 0.f ? a : expm1f(a);
  }
  __syncthreads();
  if (t == 0) {
    float a = b3[0];
    for (int i = 0; i < 16; ++i) a += h2[i] * w3[i];
    out[g] = a;
  }
}

extern "C" void kernel_launch(void* const* d_in, const int* in_sizes, int n_in,
                              void* d_out, int out_size, void* d_ws, size_t ws_size,
                              hipStream_t stream) {
  (void)in_sizes; (void)n_in; (void)out_size; (void)ws_size;
  const float* x0 = (const float*)d_in[0];
  const int* ei = (const int*)d_in[1];
  const float* ea = (const float*)d_in[2];
  const int* n2s = (const int*)d_in[3];
  const int* s2g = (const int*)d_in[4];
  const float* W1_[3] = {(const float*)d_in[5], (const float*)d_in[11], (const float*)d_in[17]};
  const float* b1_[3] = {(const float*)d_in[6], (const float*)d_in[12], (const float*)d_in[18]};
  const float* W2_[3] = {(const float*)d_in[7], (const float*)d_in[13], (const float*)d_in[19]};
  const float* b2_[3] = {(const float*)d_in[8], (const float*)d_in[14], (const float*)d_in[20]};
  const float* rt_[3] = {(const float*)d_in[9], (const float*)d_in[15], (const float*)d_in[21]};
  const float* bs_[3] = {(const float*)d_in[10], (const float*)d_in[16], (const float*)d_in[22]};
  const float* fc1w = (const float*)d_in[23]; const float* fc1b = (const float*)d_in[24];
  const float* fc2w = (const float*)d_in[25]; const float* fc2b = (const float*)d_in[26];
  const float* fc3w = (const float*)d_in[27]; const float* fc3b = (const float*)d_in[28];
  float* out = (float*)d_out;

  const int* srcp = ei;
  const int* dstp = ei + E_EDGES;

  char* wsb = (char*)d_ws;
  size_t off = 0;
  auto alloc = [&](size_t bytes) {
    void* p = wsb + off;
    off += (bytes + 255) & ~(size_t)255;
    return p;
  };
  // Kpad: L0(CI=16): 2176, L1(CI=32): 4224, L2(CI=64): 8320
  _Float16* Bsw0 = (_Float16*)alloc((size_t)2176 * 32 * 2);
  _Float16* Bsw1 = (_Float16*)alloc((size_t)4224 * 64 * 2);
  _Float16* Bsw2 = (_Float16*)alloc((size_t)8320 * 64 * 2);
  float* msgbuf = (float*)alloc((size_t)KS * E_EDGES * 64 * 4);
  float* x1 = (float*)alloc((size_t)NN * 32 * 4);
  float* x2 = (float*)alloc((size_t)NN * 64 * 4);
  int* hist = (int*)alloc((size_t)NN * 4);
  int* roff = (int*)alloc((size_t)(NN + 1) * 4);
  int* cursor = (int*)alloc((size_t)NN * 4);
  int* eidx = (int*)alloc((size_t)E_EDGES * 4);
  const int npool = 512 * 64 + 512;
  float* pools = (float*)alloc((size_t)npool * 4);
  float* ssum = pools;
  float* scnt = pools + 512 * 64;

  zero_init_k<<<(npool + 255) / 256, 256, 0, stream>>>(hist, pools, npool);
  hist_k<<<E_EDGES / 256, 256, 0, stream>>>(dstp, hist);
  scan_k<<<1, 1024, 0, stream>>>(hist, roff, cursor);
  scatter_k<<<E_EDGES / 256, 256, 0, stream>>>(dstp, cursor, eidx);
  prep_b_all_k<<<(2176 * 32 + 4224 * 64 + 8320 * 64) / 256, 256, 0, stream>>>(
      W2_[0], b2_[0], Bsw0, W2_[1], b2_[1], Bsw1, W2_[2], b2_[2], Bsw2);

  dim3 mg(E_EDGES / 128, KS);
  msg_mfma_k<16, 32><<<mg, 256, 0, stream>>>(x0, srcp, ea, W1_[0], b1_[0], Bsw0, msgbuf);
  gather_elu_k<16, 32, false><<<NN / 8, 256, 0, stream>>>(x0, rt_[0], bs_[0], msgbuf, roff, eidx, x1, nullptr, nullptr, nullptr);
  msg_mfma_k<32, 64><<<mg, 256, 0, stream>>>(x1, srcp, ea, W1_[1], b1_[1], Bsw1, msgbuf);
  gather_elu_k<32, 64, false><<<NN / 4, 256, 0, stream>>>(x1, rt_[1], bs_[1], msgbuf, roff, eidx, x2, nullptr, nullptr, nullptr);
  msg_mfma_k<64, 64><<<mg, 256, 0, stream>>>(x2, srcp, ea, W1_[2], b1_[2], Bsw2, msgbuf);
  gather_elu_k<64, 64, true><<<NN / 4, 256, 0, stream>>>(x2, rt_[2], bs_[2], msgbuf, roff, eidx, nullptr, n2s, ssum, scnt);

  pg_head_k<<<32, 64, 0, stream>>>(ssum, scnt, s2g, fc1w, fc1b, fc2w, fc2b, fc3w, fc3b, out);
}

// Round 4
// 278.265 us; speedup vs baseline: 1.0763x; 1.0721x over previous
//
#include <hip/hip_runtime.h>

#define E_EDGES 32768
#define NN 8192
#define HID 128
#define KS 4

typedef _Float16 half8 __attribute__((ext_vector_type(8)));
typedef _Float16 half4 __attribute__((ext_vector_type(4)));
typedef float f32x4 __attribute__((ext_vector_type(4)));

// ---------------- CSR build (by dst), done once per call ----------------
__global__ void zero_init_k(int* __restrict__ hist, float* __restrict__ pools, int npool) {
  int t = blockIdx.x * 256 + threadIdx.x;
  if (t < NN) hist[t] = 0;
  if (t < npool) pools[t] = 0.f;
}

__global__ void hist_k(const int* __restrict__ dst, int* __restrict__ hist) {
  int e = blockIdx.x * 256 + threadIdx.x;
  if (e < E_EDGES) atomicAdd(&hist[dst[e]], 1);
}

__global__ void scan_k(const int* __restrict__ hist, int* __restrict__ roff, int* __restrict__ cursor) {
  __shared__ int ps[1024];
  int t = threadIdx.x;
  int loc[8]; int s = 0;
  int base = t * 8;
#pragma unroll
  for (int j = 0; j < 8; ++j) { loc[j] = s; s += hist[base + j]; }
  ps[t] = s;
  __syncthreads();
  for (int off = 1; off < 1024; off <<= 1) {
    int v = 0;
    if (t >= off) v = ps[t - off];
    __syncthreads();
    if (t >= off) ps[t] += v;
    __syncthreads();
  }
  int excl = (t == 0) ? 0 : ps[t - 1];
#pragma unroll
  for (int j = 0; j < 8; ++j) { int v = excl + loc[j]; roff[base + j] = v; cursor[base + j] = v; }
  if (t == 1023) roff[NN] = ps[1023];
}

__global__ void scatter_k(const int* __restrict__ dst, int* __restrict__ cursor, int* __restrict__ eidx) {
  int e = blockIdx.x * 256 + threadIdx.x;
  if (e < E_EDGES) { int p = atomicAdd(&cursor[dst[e]], 1); eidx[p] = e; }
}

// ---------------- W2 -> f16 B-matrix, round-linear fragment layout -------
// Round = 4 chunks of k32. half8 index: h8 = ((R*4 + cr)*FC + fc)*64 + lane
// where lane = quad*16 + l15; element j in [0,8). k = (R*4+cr)*32 + quad*8+j,
// n = fc*16 + l15. k<128*CI: theta (W2[k*CO+n]); next CI rows: b2; zero pad.
// This makes (a) one round-tile a contiguous 16/8 KB region (global_load_lds
// with linear lane x 16B dest) and (b) each (chunk,fc) b-frag read a dense
// lane-contiguous 1 KB ds_read_b128 (conflict-free).
template <int CI, int CO>
__device__ inline void prep_b_one(int idx, const float* __restrict__ W2,
                                  const float* __restrict__ b2, _Float16* __restrict__ out) {
  constexpr int Kmain = 128 * CI;
  constexpr int FC = CO / 16;
  int j = idx & 7;
  int h8 = idx >> 3;
  int lane = h8 & 63;
  int quad = lane >> 4, l15 = lane & 15;
  int rest = h8 >> 6;                 // = chunk*FC + fc
  int fc = rest & (FC - 1);
  int c = rest / FC;                  // global chunk (k32)
  int k = c * 32 + quad * 8 + j;
  int n = fc * 16 + l15;
  float v = 0.f;
  if (k < Kmain) v = W2[(size_t)k * CO + n];
  else if (k < Kmain + CI) v = b2[(k - Kmain) * CO + n];
  out[idx] = (_Float16)v;
}

__global__ void prep_b_all_k(const float* __restrict__ W2_0, const float* __restrict__ b2_0, _Float16* __restrict__ o0,
                             const float* __restrict__ W2_1, const float* __restrict__ b2_1, _Float16* __restrict__ o1,
                             const float* __restrict__ W2_2, const float* __restrict__ b2_2, _Float16* __restrict__ o2) {
  constexpr int N0 = 2176 * 32;
  constexpr int N1 = 4224 * 64;
  constexpr int N2 = 8320 * 64;
  int idx = blockIdx.x * 256 + threadIdx.x;
  if (idx < N0) prep_b_one<16, 32>(idx, W2_0, b2_0, o0);
  else if (idx < N0 + N1) prep_b_one<32, 64>(idx - N0, W2_1, b2_1, o1);
  else if (idx < N0 + N1 + N2) prep_b_one<64, 64>(idx - N0 - N1, W2_2, b2_2, o2);
}

__device__ inline half8 pack8(float4 a, float4 b) {
  half8 r;
  r[0] = (_Float16)a.x; r[1] = (_Float16)a.y; r[2] = (_Float16)a.z; r[3] = (_Float16)a.w;
  r[4] = (_Float16)b.x; r[5] = (_Float16)b.y; r[6] = (_Float16)b.z; r[7] = (_Float16)b.w;
  return r;
}

// async global->LDS, 16 B per lane, linear dest (wave-uniform base + lane*16)
__device__ __forceinline__ void gload_lds16(const _Float16* g, _Float16* l) {
  __builtin_amdgcn_global_load_lds(
      (__attribute__((address_space(1))) void*)(size_t)(const void*)g,
      (__attribute__((address_space(3))) void*)(size_t)(void*)l, 16, 0, 0);
}

// ---------------- main fused kernel: edge MLP1 + Z@W2r GEMM (split-K=4) ---
// ME=256, 4 waves x 64 edges (fr=4). B round-tiles (4 chunks, 16/8 KB) are
// staged once per BLOCK into double-buffered LDS via global_load_lds and
// shared by all 4 waves (round-3 counters showed ~1 GB/dispatch of L2 B
// traffic = latency+BW bound at 26% MfmaUtil; LDS sharing cuts L2 16x).
// Counted vmcnt(FC) per round -- never 0 mid-loop (in-order vmcnt retire:
// stage(r) is guaranteed done while stage(r+1)'s FC loads stay in flight).
// 2 raw s_barriers/round; ds_read b-frags are dense lane-contiguous b128.
template <int CI, int CO>
__launch_bounds__(256, 2)
__global__ void msg_mfma_k(const float* __restrict__ xcur, const int* __restrict__ src,
                           const float* __restrict__ eattr, const float* __restrict__ W1,
                           const float* __restrict__ b1, const _Float16* __restrict__ Bsw,
                           float* __restrict__ msgbuf) {
  constexpr int ME = 256;                      // edges per block
  constexpr int HSTR = 36;                     // he [e][36] f16: 72B rows (odd dw) -> conflict-free
  constexpr int FC = CO / 16;
  constexpr int NMAIN = CI / 4;                // main rounds per split
  constexpr int XPN = (CI == 64) ? 2 : 1;
  constexpr int RHALF = 4 * FC * 64 * 8;       // halfs per round tile (8192/4096)

  __shared__ _Float16 he_s[ME * HSTR];
  __shared__ float ea_s[ME * 5];
  __shared__ float W1s[5 * 32];
  __shared__ float b1s[32];
  __shared__ int src_s[ME];
  __shared__ _Float16 bls[2 * RHALF];          // B round double-buffer

  int t = threadIdx.x;
  int e0 = blockIdx.x * ME;
  int y = blockIdx.y;                          // split: h in [32y, 32y+32)
  int hbeg = y * 32;

  // phase 1: stage eattr rows, W1/b1 slice, src indices
  for (int j = t; j < ME * 5; j += 256) ea_s[j] = eattr[e0 * 5 + j];
  if (t < 5 * 32) W1s[t] = W1[(t >> 5) * HID + hbeg + (t & 31)];
  if (t < 32) b1s[t] = b1[hbeg + t];
  src_s[t] = src[e0 + t];
  __syncthreads();

  // phase 2: edge MLP1 (this split's 32 h). hl fastest: 2B-contiguous stores.
  for (int j = t; j < 32 * ME; j += 256) {
    int hl = j & 31, e = j >> 5;
    float v = b1s[hl];
#pragma unroll
    for (int d = 0; d < 5; ++d) v += ea_s[e * 5 + d] * W1s[d * 32 + hl];
    he_s[e * HSTR + hl] = (_Float16)fmaxf(v, 0.f);
  }
  __syncthreads();

  int lane = t & 63;
  int w = t >> 6;
  int quad = lane >> 4, l15 = lane & 15;
  int qsh = (quad >> 1) << 4;                  // CI==16 h-pair select shift
  int Rg0 = y * NMAIN;                         // first global round of split
  int NR = NMAIN + ((y == 3) ? 1 : 0);         // +1 tail round on y==3

  // one-time preload: x fragments direct from global, he row base pointers
  half8 xp[4][XPN];
  const _Float16* hbp[4];
#pragma unroll
  for (int fr = 0; fr < 4; ++fr) {
    int e = w * 64 + fr * 16 + l15;
    const float* xr = xcur + (size_t)src_s[e] * CI;
    int i0 = (CI == 16) ? ((quad & 1) * 8) : (quad * 8);
    float4 v0 = *(const float4*)(xr + i0);
    float4 v1 = *(const float4*)(xr + i0 + 4);
    xp[fr][0] = pack8(v0, v1);
    if constexpr (CI == 64) {
      float4 v2 = *(const float4*)(xr + i0 + 32);
      float4 v3 = *(const float4*)(xr + i0 + 36);
      xp[fr][1] = pack8(v2, v3);
    }
    hbp[fr] = he_s + e * HSTR;
  }

  f32x4 acc[4][FC];
#pragma unroll
  for (int fr = 0; fr < 4; ++fr)
#pragma unroll
    for (int fc = 0; fc < FC; ++fc)
#pragma unroll
      for (int r = 0; r < 4; ++r) acc[fr][fc][r] = 0.f;

  // stage one round-tile: FC x 1KB per wave, linear lane x 16B
  auto stageR = [&](int rg, int buf) {
    const _Float16* gb = Bsw + (size_t)rg * RHALF + w * (FC * 512);
    _Float16* lb = bls + buf * RHALF + w * (FC * 512);
#pragma unroll
    for (int i = 0; i < FC; ++i)
      gload_lds16(gb + i * 512 + lane * 8, lb + i * 512);
  };

  // prologue: stage rounds 0 and 1
  stageR(Rg0, 0);
  stageR(Rg0 + 1, 1);

  for (int r = 0; r < NR; ++r) {
    // wait for this round's stage; keep next round's FC loads in flight
    if (r + 1 < NR) {
      if constexpr (FC == 4) asm volatile("s_waitcnt vmcnt(4)" ::: "memory");
      else                   asm volatile("s_waitcnt vmcnt(2)" ::: "memory");
    } else {
      asm volatile("s_waitcnt vmcnt(0)" ::: "memory");
    }
    __builtin_amdgcn_s_barrier();

    const _Float16* bp = bls + (r & 1) * RHALF;
    int c0 = (Rg0 + r) * 4;

    if (r < NMAIN) {
      unsigned int hp2[4];                     // CI==64: {h0, h0+1}
      half4 hp4[4];                            // CI==32: {h0..h0+3}
      if constexpr (CI == 64) {
        int oh = (c0 >> 1) - hbeg;
#pragma unroll
        for (int fr = 0; fr < 4; ++fr) hp2[fr] = *(const unsigned int*)(hbp[fr] + oh);
      } else if constexpr (CI == 32) {
        int oh = c0 - hbeg;
#pragma unroll
        for (int fr = 0; fr < 4; ++fr) hp4[fr] = *(const half4*)(hbp[fr] + oh);
      }
#pragma unroll
      for (int cr = 0; cr < 4; ++cr) {
        int c = c0 + cr;
        half8 a[4];
#pragma unroll
        for (int fr = 0; fr < 4; ++fr) {
          if constexpr (CI == 64) {
            unsigned short hb = (unsigned short)((cr >= 2) ? (hp2[fr] >> 16) : hp2[fr]);
            _Float16 hv = __builtin_bit_cast(_Float16, hb);
            a[fr] = xp[fr][cr & 1] * hv;
          } else if constexpr (CI == 32) {
            a[fr] = xp[fr][0] * hp4[fr][cr];
          } else {
            unsigned int hw = *(const unsigned int*)(hbp[fr] + (2 * c - hbeg));
            _Float16 hv = __builtin_bit_cast(_Float16, (unsigned short)(hw >> qsh));
            a[fr] = xp[fr][0] * hv;
          }
        }
#pragma unroll
        for (int fc = 0; fc < FC; ++fc) {
          half8 bf = *(const half8*)&bp[((cr * FC + fc) * 64 + lane) * 8];
#pragma unroll
          for (int fr = 0; fr < 4; ++fr)
            acc[fr][fc] = __builtin_amdgcn_mfma_f32_16x16x32_f16(a[fr], bf, acc[fr][fc], 0, 0, 0);
        }
      }
    } else {
      // tail round (y==3): b2 rows, he == 1; B zero-padded beyond CI rows
#pragma unroll
      for (int cr = 0; cr < 4; ++cr) {
        half8 a[4];
#pragma unroll
        for (int fr = 0; fr < 4; ++fr) a[fr] = xp[fr][(CI == 64) ? (cr & 1) : 0];
#pragma unroll
        for (int fc = 0; fc < FC; ++fc) {
          half8 bf = *(const half8*)&bp[((cr * FC + fc) * 64 + lane) * 8];
#pragma unroll
          for (int fr = 0; fr < 4; ++fr)
            acc[fr][fc] = __builtin_amdgcn_mfma_f32_16x16x32_f16(a[fr], bf, acc[fr][fc], 0, 0, 0);
        }
      }
    }

    // all ds_reads of this buffer complete before anyone re-stages it
    asm volatile("s_waitcnt lgkmcnt(0)" ::: "memory");
    __builtin_amdgcn_s_barrier();
    if (r + 2 < NR) stageR(Rg0 + r + 2, r & 1);
  }

  // epilogue: streaming partial writes; C/D: row(e)=quad*4+r, col(o)=l15
  float* mb = msgbuf + ((size_t)y * E_EDGES + e0) * CO;
#pragma unroll
  for (int fr = 0; fr < 4; ++fr)
#pragma unroll
    for (int fc = 0; fc < FC; ++fc)
#pragma unroll
      for (int r = 0; r < 4; ++r) {
        int el = w * 64 + fr * 16 + quad * 4 + r;
        int o = fc * 16 + l15;
        mb[el * CO + o] = acc[fr][fc][r];
      }
}

// ---------------- scatter-sum via CSR gather + x@root + bias + ELU --------
// POOL=true (last layer): skip x-write, atomically accumulate subgraph pools.
template <int CI, int CO, bool POOL>
__global__ void gather_elu_k(const float* __restrict__ xcur, const float* __restrict__ root,
                             const float* __restrict__ bias, const float* __restrict__ msgbuf,
                             const int* __restrict__ roff, const int* __restrict__ eidx,
                             float* __restrict__ xnext, const int* __restrict__ n2s,
                             float* __restrict__ ssum, float* __restrict__ scnt) {
  constexpr int NB = 256 / CO;
  __shared__ float xs[NB * CI];
  int t = threadIdx.x;
  int n0 = blockIdx.x * NB;
  for (int j = t; j < NB * CI; j += 256) xs[j] = xcur[n0 * CI + j];
  __syncthreads();
  int nl = t / CO, o = t & (CO - 1);
  int n = n0 + nl;
  float a = bias[o];
#pragma unroll
  for (int i = 0; i < CI; ++i) a += xs[nl * CI + i] * root[i * CO + o];
  int j1 = roff[n + 1];
  for (int j = roff[n]; j < j1; ++j) {
    int e = eidx[j];
    float m = 0.f;
#pragma unroll
    for (int s = 0; s < KS; ++s) m += msgbuf[((size_t)s * E_EDGES + e) * CO + o];
    a += m;
  }
  float v = a > 0.f ? a : expm1f(a);
  if constexpr (POOL) {
    int s = n2s[n];
    atomicAdd(&ssum[(s << 6) + o], v);
    if (o == 0) atomicAdd(&scnt[s], 1.f);
  } else {
    xnext[n * CO + o] = v;
  }
}

// ---------------- graph pooling + MLP head (fused) ------------------------
__global__ void pg_head_k(const float* __restrict__ ssum, const float* __restrict__ scnt,
                          const int* __restrict__ s2g,
                          const float* __restrict__ w1, const float* __restrict__ b1,
                          const float* __restrict__ w2, const float* __restrict__ b2,
                          const float* __restrict__ w3, const float* __restrict__ b3,
                          float* __restrict__ out) {
  int g = blockIdx.x;
  int t = threadIdx.x;  // 64 threads
  __shared__ int s2s[512];
  __shared__ float hm[64], h1[32], h2[16];
  for (int i = t; i < 512; i += 64) s2s[i] = s2g[i];
  __syncthreads();
  float acc = 0.f, cnt = 0.f;
  for (int s = 0; s < 512; ++s) {
    if (s2s[s] == g) {
      acc += ssum[(s << 6) + t] / fmaxf(scnt[s], 1.f);
      cnt += 1.f;
    }
  }
  hm[t] = acc / fmaxf(cnt, 1.f);
  __syncthreads();
  if (t < 32) {
    float a = b1[t];
    for (int i = 0; i < 64; ++i) a += hm[i] * w1[i * 32 + t];
    h1[t] = a > 0.f ? a : expm1f(a);
  }
  __syncthreads();
  if (t < 16) {
    float a = b2[t];
    for (int i = 0; i < 32; ++i) a += h1[i] * w2[i * 16 + t];
    h2[t] = a > 0.f ? a : expm1f(a);
  }
  __syncthreads();
  if (t == 0) {
    float a = b3[0];
    for (int i = 0; i < 16; ++i) a += h2[i] * w3[i];
    out[g] = a;
  }
}

extern "C" void kernel_launch(void* const* d_in, const int* in_sizes, int n_in,
                              void* d_out, int out_size, void* d_ws, size_t ws_size,
                              hipStream_t stream) {
  (void)in_sizes; (void)n_in; (void)out_size; (void)ws_size;
  const float* x0 = (const float*)d_in[0];
  const int* ei = (const int*)d_in[1];
  const float* ea = (const float*)d_in[2];
  const int* n2s = (const int*)d_in[3];
  const int* s2g = (const int*)d_in[4];
  const float* W1_[3] = {(const float*)d_in[5], (const float*)d_in[11], (const float*)d_in[17]};
  const float* b1_[3] = {(const float*)d_in[6], (const float*)d_in[12], (const float*)d_in[18]};
  const float* W2_[3] = {(const float*)d_in[7], (const float*)d_in[13], (const float*)d_in[19]};
  const float* b2_[3] = {(const float*)d_in[8], (const float*)d_in[14], (const float*)d_in[20]};
  const float* rt_[3] = {(const float*)d_in[9], (const float*)d_in[15], (const float*)d_in[21]};
  const float* bs_[3] = {(const float*)d_in[10], (const float*)d_in[16], (const float*)d_in[22]};
  const float* fc1w = (const float*)d_in[23]; const float* fc1b = (const float*)d_in[24];
  const float* fc2w = (const float*)d_in[25]; const float* fc2b = (const float*)d_in[26];
  const float* fc3w = (const float*)d_in[27]; const float* fc3b = (const float*)d_in[28];
  float* out = (float*)d_out;

  const int* srcp = ei;
  const int* dstp = ei + E_EDGES;

  char* wsb = (char*)d_ws;
  size_t off = 0;
  auto alloc = [&](size_t bytes) {
    void* p = wsb + off;
    off += (bytes + 255) & ~(size_t)255;
    return p;
  };
  // Kpad: L0(CI=16): 2176, L1(CI=32): 4224, L2(CI=64): 8320
  _Float16* Bsw0 = (_Float16*)alloc((size_t)2176 * 32 * 2);
  _Float16* Bsw1 = (_Float16*)alloc((size_t)4224 * 64 * 2);
  _Float16* Bsw2 = (_Float16*)alloc((size_t)8320 * 64 * 2);
  float* msgbuf = (float*)alloc((size_t)KS * E_EDGES * 64 * 4);
  float* x1 = (float*)alloc((size_t)NN * 32 * 4);
  float* x2 = (float*)alloc((size_t)NN * 64 * 4);
  int* hist = (int*)alloc((size_t)NN * 4);
  int* roff = (int*)alloc((size_t)(NN + 1) * 4);
  int* cursor = (int*)alloc((size_t)NN * 4);
  int* eidx = (int*)alloc((size_t)E_EDGES * 4);
  const int npool = 512 * 64 + 512;
  float* pools = (float*)alloc((size_t)npool * 4);
  float* ssum = pools;
  float* scnt = pools + 512 * 64;

  zero_init_k<<<(npool + 255) / 256, 256, 0, stream>>>(hist, pools, npool);
  hist_k<<<E_EDGES / 256, 256, 0, stream>>>(dstp, hist);
  scan_k<<<1, 1024, 0, stream>>>(hist, roff, cursor);
  scatter_k<<<E_EDGES / 256, 256, 0, stream>>>(dstp, cursor, eidx);
  prep_b_all_k<<<(2176 * 32 + 4224 * 64 + 8320 * 64) / 256, 256, 0, stream>>>(
      W2_[0], b2_[0], Bsw0, W2_[1], b2_[1], Bsw1, W2_[2], b2_[2], Bsw2);

  dim3 mg(E_EDGES / 256, KS);
  msg_mfma_k<16, 32><<<mg, 256, 0, stream>>>(x0, srcp, ea, W1_[0], b1_[0], Bsw0, msgbuf);
  gather_elu_k<16, 32, false><<<NN / 8, 256, 0, stream>>>(x0, rt_[0], bs_[0], msgbuf, roff, eidx, x1, nullptr, nullptr, nullptr);
  msg_mfma_k<32, 64><<<mg, 256, 0, stream>>>(x1, srcp, ea, W1_[1], b1_[1], Bsw1, msgbuf);
  gather_elu_k<32, 64, false><<<NN / 4, 256, 0, stream>>>(x1, rt_[1], bs_[1], msgbuf, roff, eidx, x2, nullptr, nullptr, nullptr);
  msg_mfma_k<64, 64><<<mg, 256, 0, stream>>>(x2, srcp, ea, W1_[2], b1_[2], Bsw2, msgbuf);
  gather_elu_k<64, 64, true><<<NN / 4, 256, 0, stream>>>(x2, rt_[2], bs_[2], msgbuf, roff, eidx, nullptr, n2s, ssum, scnt);

  pg_head_k<<<32, 64, 0, stream>>>(ssum, scnt, s2g, fc1w, fc1b, fc2w, fc2b, fc3w, fc3b, out);
}